// Round 6
// baseline (191.513 us; speedup 1.0000x reference)
//
#include <hip/hip_runtime.h>

#define N_NODES 8192
#define D_IN 512
#define D_OUT 64
#define LRELU_ALPHA 0.2f
#define BK 256
#define KSPLIT 8
#define KSLICE (N_NODES / KSPLIT)   // 1024 columns per block
#define NSLICES (KSPLIT * 4)        // 32 per-wave partial slices

typedef __attribute__((ext_vector_type(8))) short bf16x8;
typedef __attribute__((ext_vector_type(4))) float f32x4;

__device__ __forceinline__ unsigned short f2bf(float x) {
    unsigned u = __float_as_uint(x);
    u += 0x7fffu + ((u >> 16) & 1u);   // round-to-nearest-even
    return (unsigned short)(u >> 16);
}

__device__ __forceinline__ float pcalc(float mk, float w2, float wh1v, float& lsum) {
    float e = wh1v + w2;
    e = fmaxf(e, LRELU_ALPHA * e);   // LeakyReLU (monotone)
    float p = mk * __expf(e);        // mask is exactly 0.0/1.0; |e|<=~24 f32-safe
    lsum += p;
    return p;
}

__device__ __forceinline__ bf16x8 ldb(const unsigned short* p) {
    ushort4 lo = *(const ushort4*)p;          // k+0..3
    ushort4 hi = *(const ushort4*)(p + 16);   // k+16..19
    bf16x8 r;
    r[0] = (short)lo.x; r[1] = (short)lo.y; r[2] = (short)lo.z; r[3] = (short)lo.w;
    r[4] = (short)hi.x; r[5] = (short)hi.y; r[6] = (short)hi.z; r[7] = (short)hi.w;
    return r;
}

// ---------------- Kernel 1: Wh = h @ W; epilogue writes WhT(bf16), Wh1, Wh2 ----------------
__global__ __launch_bounds__(256) void k_gemm_wh(const float* __restrict__ h,
                                                 const float* __restrict__ W,
                                                 const float* __restrict__ a,
                                                 unsigned short* __restrict__ WhT,
                                                 float* __restrict__ Wh1,
                                                 float* __restrict__ Wh2) {
    __shared__ float hs[32][68];
    __shared__ float Ws[64][64];
    const int tid = threadIdx.x;
    const int r0 = blockIdx.x * 32;
    const int tf = tid & 15;
    const int tr = tid >> 4;
    float acc[2][4] = {{0.f,0.f,0.f,0.f},{0.f,0.f,0.f,0.f}};

    for (int kc = 0; kc < D_IN; kc += 64) {
        {
            int rr = tid >> 4;
            int cc = (tid & 15) * 4;
            float4 v0 = *(const float4*)&h[(size_t)(r0 + rr) * D_IN + kc + cc];
            float4 v1 = *(const float4*)&h[(size_t)(r0 + rr + 16) * D_IN + kc + cc];
            *(float4*)&hs[rr][cc] = v0;
            *(float4*)&hs[rr + 16][cc] = v1;
        }
        #pragma unroll
        for (int p = 0; p < 4; ++p) {
            int kk = (tid >> 4) + p * 16;
            int cc = (tid & 15) * 4;
            *(float4*)&Ws[kk][cc] = *(const float4*)&W[(size_t)(kc + kk) * D_OUT + cc];
        }
        __syncthreads();
        #pragma unroll
        for (int k = 0; k < 64; k += 4) {
            float4 a0 = *(const float4*)&hs[tr*2][k];
            float4 a1 = *(const float4*)&hs[tr*2+1][k];
            float av0[4] = {a0.x, a0.y, a0.z, a0.w};
            float av1[4] = {a1.x, a1.y, a1.z, a1.w};
            #pragma unroll
            for (int kk = 0; kk < 4; ++kk) {
                float4 b = *(const float4*)&Ws[k+kk][tf*4];
                acc[0][0] += av0[kk]*b.x; acc[0][1] += av0[kk]*b.y;
                acc[0][2] += av0[kk]*b.z; acc[0][3] += av0[kk]*b.w;
                acc[1][0] += av1[kk]*b.x; acc[1][1] += av1[kk]*b.y;
                acc[1][2] += av1[kk]*b.z; acc[1][3] += av1[kk]*b.w;
            }
        }
        __syncthreads();
    }
    const int orow = r0 + tr*2;

    #pragma unroll
    for (int k = 0; k < 4; ++k) {
        unsigned v = (unsigned)f2bf(acc[0][k]) | ((unsigned)f2bf(acc[1][k]) << 16);
        *(unsigned*)&WhT[(size_t)(tf*4 + k) * N_NODES + orow] = v;
    }

    float a1v[4], a2v[4];
    #pragma unroll
    for (int k = 0; k < 4; ++k) { a1v[k] = a[tf*4 + k]; a2v[k] = a[64 + tf*4 + k]; }
    float s1 = 0.f, t1 = 0.f, s2 = 0.f, t2 = 0.f;
    #pragma unroll
    for (int k = 0; k < 4; ++k) {
        s1 += acc[0][k] * a1v[k];
        t1 += acc[1][k] * a1v[k];
        s2 += acc[0][k] * a2v[k];
        t2 += acc[1][k] * a2v[k];
    }
    #pragma unroll
    for (int d = 1; d < 16; d <<= 1) {
        s1 += __shfl_xor(s1, d);
        t1 += __shfl_xor(t1, d);
        s2 += __shfl_xor(s2, d);
        t2 += __shfl_xor(t2, d);
    }
    if (tf == 0) {
        Wh1[orow] = s1; Wh1[orow + 1] = t1;
        Wh2[orow] = s2; Wh2[orow + 1] = t2;
    }
}

// ---------------- Kernel 2: dense masked-softmax-numerator + PV partials via MFMA ----------------
// Grid = 512 row-blocks x KSPLIT. ZERO LDS, zero barriers: each wave writes its own
// 16x64 f32 partial. Straight-line 4-chunk body with sched_barrier(0) fences pinning
// {B-loads} -> {next mask/Wh2 prefetch} -> {VALU+MFMA} issue order so the register
// double-buffer survives regalloc (R4: compiler sank loads, VGPR=56, fully serialized).
__global__ __launch_bounds__(256, 3) void k_attn(const float* __restrict__ mask,
                                                 const unsigned short* __restrict__ WhT,
                                                 const float* __restrict__ Wh1,
                                                 const float* __restrict__ Wh2,
                                                 float* __restrict__ pacc,
                                                 float* __restrict__ plsum) {
    const int wave = threadIdx.x >> 6;
    const int lane = threadIdx.x & 63;
    const int i16 = lane & 15;
    const int g   = lane >> 4;
    const int rowblk = blockIdx.x >> 3;
    const int kslice = blockIdx.x & 7;
    const int R   = rowblk * 16;

    const float wh1v = Wh1[R + i16];
    const float* mrow = mask + (size_t)(R + i16) * N_NODES + kslice * KSLICE;
    const float* w2base = Wh2 + kslice * KSLICE;
    const unsigned short* brow = WhT + kslice * KSLICE + (size_t)i16 * N_NODES;
    const int kwoff = wave * 64 + g * 4;

    f32x4 acc0 = {0.f,0.f,0.f,0.f}, acc1 = {0.f,0.f,0.f,0.f};
    f32x4 acc2 = {0.f,0.f,0.f,0.f}, acc3 = {0.f,0.f,0.f,0.f};
    float lsum = 0.f;
    bf16x8 B00, B10, B01, B11, B02, B12, B03, B13;

#define SB() __builtin_amdgcn_sched_barrier(0)

#define LOADMW(cidx, M0,M1,M2,M3, W0,W1,W2,W3)                      \
    {                                                               \
        const int co_ = (cidx) * BK + kwoff;                        \
        const float4* mp_ = (const float4*)(mrow + co_);            \
        const float4* wp_ = (const float4*)(w2base + co_);          \
        M0 = mp_[0]; M1 = mp_[4]; M2 = mp_[8]; M3 = mp_[12];        \
        W0 = wp_[0]; W1 = wp_[4]; W2 = wp_[8]; W3 = wp_[12];        \
    }

#define BLD(cidx)                                                   \
    {                                                               \
        const unsigned short* bb_ = brow + (cidx) * BK + kwoff;     \
        B00 = ldb(bb_);                                             \
        B10 = ldb(bb_ + 32);                                        \
        B01 = ldb(bb_ + 16 * N_NODES);                              \
        B11 = ldb(bb_ + 16 * N_NODES + 32);                         \
        B02 = ldb(bb_ + 32 * N_NODES);                              \
        B12 = ldb(bb_ + 32 * N_NODES + 32);                         \
        B03 = ldb(bb_ + 48 * N_NODES);                              \
        B13 = ldb(bb_ + 48 * N_NODES + 32);                         \
    }

#define PCMF(M0,M1,M2,M3, W0,W1,W2,W3)                                            \
    {                                                                             \
        bf16x8 af0, af1;                                                          \
        af0[0]=(short)f2bf(pcalc(M0.x,W0.x,wh1v,lsum));                           \
        af0[1]=(short)f2bf(pcalc(M0.y,W0.y,wh1v,lsum));                           \
        af0[2]=(short)f2bf(pcalc(M0.z,W0.z,wh1v,lsum));                           \
        af0[3]=(short)f2bf(pcalc(M0.w,W0.w,wh1v,lsum));                           \
        af0[4]=(short)f2bf(pcalc(M1.x,W1.x,wh1v,lsum));                           \
        af0[5]=(short)f2bf(pcalc(M1.y,W1.y,wh1v,lsum));                           \
        af0[6]=(short)f2bf(pcalc(M1.z,W1.z,wh1v,lsum));                           \
        af0[7]=(short)f2bf(pcalc(M1.w,W1.w,wh1v,lsum));                           \
        af1[0]=(short)f2bf(pcalc(M2.x,W2.x,wh1v,lsum));                           \
        af1[1]=(short)f2bf(pcalc(M2.y,W2.y,wh1v,lsum));                           \
        af1[2]=(short)f2bf(pcalc(M2.z,W2.z,wh1v,lsum));                           \
        af1[3]=(short)f2bf(pcalc(M2.w,W2.w,wh1v,lsum));                           \
        af1[4]=(short)f2bf(pcalc(M3.x,W3.x,wh1v,lsum));                           \
        af1[5]=(short)f2bf(pcalc(M3.y,W3.y,wh1v,lsum));                           \
        af1[6]=(short)f2bf(pcalc(M3.z,W3.z,wh1v,lsum));                           \
        af1[7]=(short)f2bf(pcalc(M3.w,W3.w,wh1v,lsum));                           \
        acc0 = __builtin_amdgcn_mfma_f32_16x16x32_bf16(af0, B00, acc0, 0, 0, 0);  \
        acc1 = __builtin_amdgcn_mfma_f32_16x16x32_bf16(af0, B01, acc1, 0, 0, 0);  \
        acc2 = __builtin_amdgcn_mfma_f32_16x16x32_bf16(af0, B02, acc2, 0, 0, 0);  \
        acc3 = __builtin_amdgcn_mfma_f32_16x16x32_bf16(af0, B03, acc3, 0, 0, 0);  \
        acc0 = __builtin_amdgcn_mfma_f32_16x16x32_bf16(af1, B10, acc0, 0, 0, 0);  \
        acc1 = __builtin_amdgcn_mfma_f32_16x16x32_bf16(af1, B11, acc1, 0, 0, 0);  \
        acc2 = __builtin_amdgcn_mfma_f32_16x16x32_bf16(af1, B12, acc2, 0, 0, 0);  \
        acc3 = __builtin_amdgcn_mfma_f32_16x16x32_bf16(af1, B13, acc3, 0, 0, 0);  \
    }

    float4 mA0,mA1,mA2,mA3, wA0,wA1,wA2,wA3;
    float4 mB0,mB1,mB2,mB3, wB0,wB1,wB2,wB3;

    // straight-line 4-chunk pinned pipeline (KSLICE/BK == 4)
    LOADMW(0, mA0,mA1,mA2,mA3, wA0,wA1,wA2,wA3);  SB();
    BLD(0);                                       SB();
    LOADMW(1, mB0,mB1,mB2,mB3, wB0,wB1,wB2,wB3);  SB();
    PCMF(mA0,mA1,mA2,mA3, wA0,wA1,wA2,wA3);       SB();
    BLD(1);                                       SB();
    LOADMW(2, mA0,mA1,mA2,mA3, wA0,wA1,wA2,wA3);  SB();
    PCMF(mB0,mB1,mB2,mB3, wB0,wB1,wB2,wB3);       SB();
    BLD(2);                                       SB();
    LOADMW(3, mB0,mB1,mB2,mB3, wB0,wB1,wB2,wB3);  SB();
    PCMF(mA0,mA1,mA2,mA3, wA0,wA1,wA2,wA3);       SB();
    BLD(3);                                       SB();
    PCMF(mB0,mB1,mB2,mB3, wB0,wB1,wB2,wB3);

#undef LOADMW
#undef BLD
#undef PCMF
#undef SB

    // sum lsum across the 4 g-subgroups holding the same row
    lsum += __shfl_xor(lsum, 16);
    lsum += __shfl_xor(lsum, 32);

    // per-wave partial slice = kslice*4 + wave; D layout: row = g*4+r, col = q*16+i16
    const size_t srow = ((size_t)(kslice * 4 + wave) * N_NODES + R);
    #pragma unroll
    for (int r = 0; r < 4; ++r) {
        float* pr = pacc + (srow + g*4 + r) * D_OUT + i16;
        pr[ 0] = acc0[r];
        pr[16] = acc1[r];
        pr[32] = acc2[r];
        pr[48] = acc3[r];
    }
    if (lane < 16) plsum[srow + lane] = lsum;
}

// ---------------- Kernel 3: sum NSLICES partials, normalize, ELU ----------------
__global__ __launch_bounds__(256) void k_finish(const float* __restrict__ pacc,
                                                const float* __restrict__ plsum,
                                                float* __restrict__ out) {
    const int idx = blockIdx.x * 256 + threadIdx.x;   // one float4 per thread
    const int row = idx >> 4;
    const int tf4 = (idx & 15) * 4;
    float4 s = {0.f, 0.f, 0.f, 0.f};
    float L = 0.f;
    #pragma unroll
    for (int k = 0; k < NSLICES; ++k) {
        float4 v = *(const float4*)&pacc[((size_t)k * N_NODES + row) * D_OUT + tf4];
        s.x += v.x; s.y += v.y; s.z += v.z; s.w += v.w;
        L += plsum[(size_t)k * N_NODES + row];
    }
    const float inv = (L > 0.f) ? 1.f / L : 0.f;
    float4 o;
    o.x = s.x * inv; o.y = s.y * inv; o.z = s.z * inv; o.w = s.w * inv;
    o.x = (o.x > 0.f) ? o.x : (__expf(o.x) - 1.f);
    o.y = (o.y > 0.f) ? o.y : (__expf(o.y) - 1.f);
    o.z = (o.z > 0.f) ? o.z : (__expf(o.z) - 1.f);
    o.w = (o.w > 0.f) ? o.w : (__expf(o.w) - 1.f);
    *(float4*)&out[(size_t)row * D_OUT + tf4] = o;
}

extern "C" void kernel_launch(void* const* d_in, const int* in_sizes, int n_in,
                              void* d_out, int out_size, void* d_ws, size_t ws_size,
                              hipStream_t stream) {
    const float* h    = (const float*)d_in[0];
    const float* mask = (const float*)d_in[1];
    // d_in[2] = lamda: unused (dischange==0 makes the mask-update a no-op)
    const float* W    = (const float*)d_in[3];
    const float* a    = (const float*)d_in[4];
    float* out = (float*)d_out;

    // ws: WhT bf16 [64][8192] (1MB) | Wh1 [8192] | Wh2 [8192] | pacc f32 [32][8192][64] (64MB) | plsum [32][8192] (1MB)
    unsigned short* WhT = (unsigned short*)d_ws;
    float* Wh1 = (float*)((char*)d_ws + (size_t)D_OUT * N_NODES * sizeof(unsigned short));
    float* Wh2 = Wh1 + N_NODES;
    float* pacc = Wh2 + N_NODES;
    float* plsum = pacc + (size_t)NSLICES * N_NODES * D_OUT;

    k_gemm_wh<<<N_NODES / 32, 256, 0, stream>>>(h, W, a, WhT, Wh1, Wh2);
    k_attn<<<(N_NODES / 16) * KSPLIT, 256, 0, stream>>>(mask, WhT, Wh1, Wh2, pacc, plsum);
    k_finish<<<(N_NODES * D_OUT / 4) / 256, 256, 0, stream>>>(pacc, plsum, out);
}

// Round 7
// 158.859 us; speedup vs baseline: 1.2056x; 1.2056x over previous
//
#include <hip/hip_runtime.h>

#define N_NODES 8192
#define D_IN 512
#define D_OUT 64
#define LRELU_ALPHA 0.2f
#define KSPLIT 8
#define KSLICE (N_NODES / KSPLIT)   // 1024 cols per k-slice

typedef __attribute__((ext_vector_type(8))) short bf16x8;
typedef __attribute__((ext_vector_type(4))) float f32x4;

__device__ __forceinline__ unsigned short f2bf(float x) {
    unsigned u = __float_as_uint(x);
    u += 0x7fffu + ((u >> 16) & 1u);   // round-to-nearest-even
    return (unsigned short)(u >> 16);
}

// ---------------- Kernel 0: mask f32 (256MB) -> bitmask (8MB) ----------------
// Pure stream, ballot-packed. Word layout per 256-col group: 4 u64 words, word d,
// bit l  <->  col = group*256 + l*4 + d  (float4 component d, lane l).
__global__ __launch_bounds__(256) void k_maskbits(const float* __restrict__ mask,
                                                  unsigned long long* __restrict__ bits) {
    const int wave = threadIdx.x >> 6;
    const int lane = threadIdx.x & 63;
    const int row = blockIdx.x * 4 + wave;
    const float4* m4 = (const float4*)(mask + (size_t)row * N_NODES);
    unsigned long long* brow = bits + (size_t)row * (N_NODES / 64);
    for (int it = 0; it < 32; ++it) {
        float4 mk = m4[it * 64 + lane];
        unsigned long long b0 = __ballot(mk.x > 0.f);
        unsigned long long b1 = __ballot(mk.y > 0.f);
        unsigned long long b2 = __ballot(mk.z > 0.f);
        unsigned long long b3 = __ballot(mk.w > 0.f);
        if (lane == 0) {
            ulonglong2 t0; t0.x = b0; t0.y = b1;
            ulonglong2 t1; t1.x = b2; t1.y = b3;
            *(ulonglong2*)(brow + it * 4)     = t0;
            *(ulonglong2*)(brow + it * 4 + 2) = t1;
        }
    }
}

// ---------------- Kernel 1: Wh = h @ W; epilogue writes WhTp(bf16, frag-order), Wh1, Wh2 ----------------
// WhTp layout: per feature n, per 64-col block: shorts [half(m>>1)*32 + g*8 + (m&1)*4 + d]
// where col_in_block = g*4 + 16m + d  ->  each MFMA B fragment is one contiguous 16B.
__global__ __launch_bounds__(256) void k_gemm_wh(const float* __restrict__ h,
                                                 const float* __restrict__ W,
                                                 const float* __restrict__ a,
                                                 unsigned short* __restrict__ WhTp,
                                                 float* __restrict__ Wh1,
                                                 float* __restrict__ Wh2) {
    __shared__ float hs[32][68];
    __shared__ float Ws[64][64];
    const int tid = threadIdx.x;
    const int r0 = blockIdx.x * 32;
    const int tf = tid & 15;
    const int tr = tid >> 4;
    float acc[2][4] = {{0.f,0.f,0.f,0.f},{0.f,0.f,0.f,0.f}};

    for (int kc = 0; kc < D_IN; kc += 64) {
        {
            int rr = tid >> 4;
            int cc = (tid & 15) * 4;
            float4 v0 = *(const float4*)&h[(size_t)(r0 + rr) * D_IN + kc + cc];
            float4 v1 = *(const float4*)&h[(size_t)(r0 + rr + 16) * D_IN + kc + cc];
            *(float4*)&hs[rr][cc] = v0;
            *(float4*)&hs[rr + 16][cc] = v1;
        }
        #pragma unroll
        for (int p = 0; p < 4; ++p) {
            int kk = (tid >> 4) + p * 16;
            int cc = (tid & 15) * 4;
            *(float4*)&Ws[kk][cc] = *(const float4*)&W[(size_t)(kc + kk) * D_OUT + cc];
        }
        __syncthreads();
        #pragma unroll
        for (int k = 0; k < 64; k += 4) {
            float4 a0 = *(const float4*)&hs[tr*2][k];
            float4 a1 = *(const float4*)&hs[tr*2+1][k];
            float av0[4] = {a0.x, a0.y, a0.z, a0.w};
            float av1[4] = {a1.x, a1.y, a1.z, a1.w};
            #pragma unroll
            for (int kk = 0; kk < 4; ++kk) {
                float4 b = *(const float4*)&Ws[k+kk][tf*4];
                acc[0][0] += av0[kk]*b.x; acc[0][1] += av0[kk]*b.y;
                acc[0][2] += av0[kk]*b.z; acc[0][3] += av0[kk]*b.w;
                acc[1][0] += av1[kk]*b.x; acc[1][1] += av1[kk]*b.y;
                acc[1][2] += av1[kk]*b.z; acc[1][3] += av1[kk]*b.w;
            }
        }
        __syncthreads();
    }
    const int orow = r0 + tr*2;   // even

    // permuted WhTp write: cols (orow, orow+1) share (g,m), d even -> one 4B store
    {
        const int blk = orow >> 6;
        const int cw  = orow & 63;
        const int d   = cw & 3;
        const int gg  = (cw >> 2) & 3;
        const int m   = cw >> 4;
        const int soff = blk * 64 + (m >> 1) * 32 + gg * 8 + (m & 1) * 4 + d;
        #pragma unroll
        for (int k = 0; k < 4; ++k) {
            unsigned v = (unsigned)f2bf(acc[0][k]) | ((unsigned)f2bf(acc[1][k]) << 16);
            *(unsigned*)&WhTp[(size_t)(tf*4 + k) * N_NODES + soff] = v;
        }
    }

    float a1v[4], a2v[4];
    #pragma unroll
    for (int k = 0; k < 4; ++k) { a1v[k] = a[tf*4 + k]; a2v[k] = a[64 + tf*4 + k]; }
    float s1 = 0.f, t1 = 0.f, s2 = 0.f, t2 = 0.f;
    #pragma unroll
    for (int k = 0; k < 4; ++k) {
        s1 += acc[0][k] * a1v[k];
        t1 += acc[1][k] * a1v[k];
        s2 += acc[0][k] * a2v[k];
        t2 += acc[1][k] * a2v[k];
    }
    #pragma unroll
    for (int d = 1; d < 16; d <<= 1) {
        s1 += __shfl_xor(s1, d);
        t1 += __shfl_xor(t1, d);
        s2 += __shfl_xor(s2, d);
        t2 += __shfl_xor(t2, d);
    }
    if (tf == 0) {
        Wh1[orow] = s1; Wh1[orow + 1] = t1;
        Wh2[orow] = s2; Wh2[orow + 1] = t2;
    }
}

__device__ __forceinline__ float pgate(unsigned long long sd, int m, float w2v,
                                       float wh1v, float& lsum) {
    float e = wh1v + w2v;
    e = fmaxf(e, LRELU_ALPHA * e);                          // LeakyReLU
    float p = ((unsigned)(sd >> (4 * m)) & 1u) ? __expf(e) : 0.f;
    lsum += p;
    return p;
}

// ---------------- Kernel 2: bit-gated masked-softmax numerator + PV via MFMA ----------------
// Grid = 512 row-blocks x KSPLIT. Per chunk (256 cols) per lane: 2x16B bit loads (L2/L3),
// 4x16B Wh2 (L2), 8x16B B fragments (WhTp 1MB, L2-hot). The 256MB mask stream is gone.
__global__ __launch_bounds__(256, 4) void k_attn(const unsigned long long* __restrict__ bits,
                                                 const unsigned short* __restrict__ WhTp,
                                                 const float* __restrict__ Wh1,
                                                 const float* __restrict__ Wh2,
                                                 float* __restrict__ pacc,
                                                 float* __restrict__ plsum) {
    __shared__ float accbuf[4][16][68];
    __shared__ float lsumbuf[4][16];

    const int wave = threadIdx.x >> 6;
    const int lane = threadIdx.x & 63;
    const int i16 = lane & 15;
    const int g   = lane >> 4;
    const int rowblk = blockIdx.x >> 3;
    const int kslice = blockIdx.x & 7;
    const int R   = rowblk * 16;

    const float wh1v = Wh1[R + i16];
    const unsigned long long* bitrow =
        bits + (size_t)(R + i16) * (N_NODES / 64) + kslice * (KSLICE / 64);
    const float* wh2s = Wh2 + kslice * KSLICE + wave * 64 + g * 4;
    const unsigned short* bbase = WhTp + (size_t)i16 * N_NODES + (size_t)(kslice * 16 + wave) * 64 + g * 8;
    const int sh = wave * 16 + g;

    f32x4 acc0 = {0.f,0.f,0.f,0.f}, acc1 = {0.f,0.f,0.f,0.f};
    f32x4 acc2 = {0.f,0.f,0.f,0.f}, acc3 = {0.f,0.f,0.f,0.f};
    float lsum = 0.f;
    bf16x8 B00, B10, B01, B11, B02, B12, B03, B13;

#define LOADS(cc, W0,W1,W2,W3, U01,U23)                              \
    {                                                                \
        U01 = *(const ulonglong2*)(bitrow + (cc) * 4);               \
        U23 = *(const ulonglong2*)(bitrow + (cc) * 4 + 2);           \
        const float* wp_ = wh2s + (cc) * 256;                        \
        W0 = *(const float4*)wp_;                                    \
        W1 = *(const float4*)(wp_ + 16);                             \
        W2 = *(const float4*)(wp_ + 32);                             \
        W3 = *(const float4*)(wp_ + 48);                             \
    }

#define BLD(cc)                                                      \
    {                                                                \
        const unsigned short* bb_ = bbase + (cc) * 4 * 64;           \
        B00 = *(const bf16x8*)(bb_);                                 \
        B10 = *(const bf16x8*)(bb_ + 32);                            \
        B01 = *(const bf16x8*)(bb_ + 16 * N_NODES);                  \
        B11 = *(const bf16x8*)(bb_ + 16 * N_NODES + 32);             \
        B02 = *(const bf16x8*)(bb_ + 32 * N_NODES);                  \
        B12 = *(const bf16x8*)(bb_ + 32 * N_NODES + 32);             \
        B03 = *(const bf16x8*)(bb_ + 48 * N_NODES);                  \
        B13 = *(const bf16x8*)(bb_ + 48 * N_NODES + 32);             \
    }

#define PCMF(W0,W1,W2,W3, U01,U23)                                                \
    {                                                                             \
        const unsigned long long s0 = U01.x >> sh;                                \
        const unsigned long long s1 = U01.y >> sh;                                \
        const unsigned long long s2 = U23.x >> sh;                                \
        const unsigned long long s3 = U23.y >> sh;                                \
        bf16x8 af0, af1;                                                          \
        af0[0]=(short)f2bf(pgate(s0,0,W0.x,wh1v,lsum));                           \
        af0[1]=(short)f2bf(pgate(s1,0,W0.y,wh1v,lsum));                           \
        af0[2]=(short)f2bf(pgate(s2,0,W0.z,wh1v,lsum));                           \
        af0[3]=(short)f2bf(pgate(s3,0,W0.w,wh1v,lsum));                           \
        af0[4]=(short)f2bf(pgate(s0,1,W1.x,wh1v,lsum));                           \
        af0[5]=(short)f2bf(pgate(s1,1,W1.y,wh1v,lsum));                           \
        af0[6]=(short)f2bf(pgate(s2,1,W1.z,wh1v,lsum));                           \
        af0[7]=(short)f2bf(pgate(s3,1,W1.w,wh1v,lsum));                           \
        af1[0]=(short)f2bf(pgate(s0,2,W2.x,wh1v,lsum));                           \
        af1[1]=(short)f2bf(pgate(s1,2,W2.y,wh1v,lsum));                           \
        af1[2]=(short)f2bf(pgate(s2,2,W2.z,wh1v,lsum));                           \
        af1[3]=(short)f2bf(pgate(s3,2,W2.w,wh1v,lsum));                           \
        af1[4]=(short)f2bf(pgate(s0,3,W3.x,wh1v,lsum));                           \
        af1[5]=(short)f2bf(pgate(s1,3,W3.y,wh1v,lsum));                           \
        af1[6]=(short)f2bf(pgate(s2,3,W3.z,wh1v,lsum));                           \
        af1[7]=(short)f2bf(pgate(s3,3,W3.w,wh1v,lsum));                           \
        acc0 = __builtin_amdgcn_mfma_f32_16x16x32_bf16(af0, B00, acc0, 0, 0, 0);  \
        acc1 = __builtin_amdgcn_mfma_f32_16x16x32_bf16(af0, B01, acc1, 0, 0, 0);  \
        acc2 = __builtin_amdgcn_mfma_f32_16x16x32_bf16(af0, B02, acc2, 0, 0, 0);  \
        acc3 = __builtin_amdgcn_mfma_f32_16x16x32_bf16(af0, B03, acc3, 0, 0, 0);  \
        acc0 = __builtin_amdgcn_mfma_f32_16x16x32_bf16(af1, B10, acc0, 0, 0, 0);  \
        acc1 = __builtin_amdgcn_mfma_f32_16x16x32_bf16(af1, B11, acc1, 0, 0, 0);  \
        acc2 = __builtin_amdgcn_mfma_f32_16x16x32_bf16(af1, B12, acc2, 0, 0, 0);  \
        acc3 = __builtin_amdgcn_mfma_f32_16x16x32_bf16(af1, B13, acc3, 0, 0, 0);  \
    }

    float4 aW0,aW1,aW2,aW3, bW0,bW1,bW2,bW3;
    ulonglong2 aU01,aU23, bU01,bU23;

    LOADS(0, aW0,aW1,aW2,aW3, aU01,aU23);
    LOADS(1, bW0,bW1,bW2,bW3, bU01,bU23);
    BLD(0);
    PCMF(aW0,aW1,aW2,aW3, aU01,aU23);
    LOADS(2, aW0,aW1,aW2,aW3, aU01,aU23);
    BLD(1);
    PCMF(bW0,bW1,bW2,bW3, bU01,bU23);
    LOADS(3, bW0,bW1,bW2,bW3, bU01,bU23);
    BLD(2);
    PCMF(aW0,aW1,aW2,aW3, aU01,aU23);
    BLD(3);
    PCMF(bW0,bW1,bW2,bW3, bU01,bU23);

#undef LOADS
#undef BLD
#undef PCMF

    // sum lsum across the 4 g-subgroups holding the same row
    lsum += __shfl_xor(lsum, 16);
    lsum += __shfl_xor(lsum, 32);
    if (lane < 16) lsumbuf[wave][lane] = lsum;

    // D layout (m89): row = g*4 + r, col = i16
    #pragma unroll
    for (int r = 0; r < 4; ++r) {
        accbuf[wave][g*4 + r][ 0 + i16] = acc0[r];
        accbuf[wave][g*4 + r][16 + i16] = acc1[r];
        accbuf[wave][g*4 + r][32 + i16] = acc2[r];
        accbuf[wave][g*4 + r][48 + i16] = acc3[r];
    }
    __syncthreads();

    const int tr  = threadIdx.x >> 4;
    const int tf4 = (threadIdx.x & 15) * 4;
    float4 s0 = *(const float4*)&accbuf[0][tr][tf4];
    float4 s1 = *(const float4*)&accbuf[1][tr][tf4];
    float4 s2 = *(const float4*)&accbuf[2][tr][tf4];
    float4 s3 = *(const float4*)&accbuf[3][tr][tf4];
    float4 o;
    o.x = s0.x + s1.x + s2.x + s3.x;
    o.y = s0.y + s1.y + s2.y + s3.y;
    o.z = s0.z + s1.z + s2.z + s3.z;
    o.w = s0.w + s1.w + s2.w + s3.w;
    *(float4*)&pacc[((size_t)kslice * N_NODES + R + tr) * D_OUT + tf4] = o;
    if (threadIdx.x < 16) {
        plsum[(size_t)kslice * N_NODES + R + threadIdx.x] =
            lsumbuf[0][threadIdx.x] + lsumbuf[1][threadIdx.x] +
            lsumbuf[2][threadIdx.x] + lsumbuf[3][threadIdx.x];
    }
}

// ---------------- Kernel 3: sum KSPLIT partials, normalize, ELU ----------------
__global__ __launch_bounds__(256) void k_finish(const float* __restrict__ pacc,
                                                const float* __restrict__ plsum,
                                                float* __restrict__ out) {
    const int idx = blockIdx.x * 256 + threadIdx.x;
    const int row = idx >> 4;
    const int tf4 = (idx & 15) * 4;
    float4 s = {0.f, 0.f, 0.f, 0.f};
    float L = 0.f;
    #pragma unroll
    for (int k = 0; k < KSPLIT; ++k) {
        float4 v = *(const float4*)&pacc[((size_t)k * N_NODES + row) * D_OUT + tf4];
        s.x += v.x; s.y += v.y; s.z += v.z; s.w += v.w;
        L += plsum[(size_t)k * N_NODES + row];
    }
    const float inv = (L > 0.f) ? 1.f / L : 0.f;
    float4 o;
    o.x = s.x * inv; o.y = s.y * inv; o.z = s.z * inv; o.w = s.w * inv;
    o.x = (o.x > 0.f) ? o.x : (__expf(o.x) - 1.f);
    o.y = (o.y > 0.f) ? o.y : (__expf(o.y) - 1.f);
    o.z = (o.z > 0.f) ? o.z : (__expf(o.z) - 1.f);
    o.w = (o.w > 0.f) ? o.w : (__expf(o.w) - 1.f);
    *(float4*)&out[(size_t)row * D_OUT + tf4] = o;
}

extern "C" void kernel_launch(void* const* d_in, const int* in_sizes, int n_in,
                              void* d_out, int out_size, void* d_ws, size_t ws_size,
                              hipStream_t stream) {
    const float* h    = (const float*)d_in[0];
    const float* mask = (const float*)d_in[1];
    // d_in[2] = lamda: unused (dischange==0 makes the mask-update a no-op)
    const float* W    = (const float*)d_in[3];
    const float* a    = (const float*)d_in[4];
    float* out = (float*)d_out;

    // ws: WhTp bf16 [64][8192] (1MB) | Wh1 (32KB) | Wh2 (32KB) | bits (8MB) | pacc (16MB) | plsum (256KB)
    unsigned short* WhTp = (unsigned short*)d_ws;
    float* Wh1 = (float*)((char*)d_ws + (size_t)D_OUT * N_NODES * sizeof(unsigned short));
    float* Wh2 = Wh1 + N_NODES;
    unsigned long long* bitsw = (unsigned long long*)(Wh2 + N_NODES);
    float* pacc = (float*)(bitsw + (size_t)N_NODES * (N_NODES / 64));
    float* plsum = pacc + (size_t)KSPLIT * N_NODES * D_OUT;

    k_maskbits<<<N_NODES / 4, 256, 0, stream>>>(mask, bitsw);
    k_gemm_wh<<<N_NODES / 32, 256, 0, stream>>>(h, W, a, WhTp, Wh1, Wh2);
    k_attn<<<(N_NODES / 16) * KSPLIT, 256, 0, stream>>>(bitsw, WhTp, Wh1, Wh2, pacc, plsum);
    k_finish<<<(N_NODES * D_OUT / 4) / 256, 256, 0, stream>>>(pacc, plsum, out);
}